// Round 1
// baseline (179.002 us; speedup 1.0000x reference)
//
#include <hip/hip_runtime.h>
#include <math.h>

#define NJ 140
#define NV 13059
#define NB 512
#define NBONES 28

#define MTILES 103                    // 103*128 = 13184 >= NV
#define NBLK 12                       // 1536 / 128
#define KS 18                         // K = 576 = 18*32
#define GRID_GEMM (MTILES*NBLK)       // 1236

#define APREP_SLOTS (MTILES*KS*512)   // 949248 f16x8 slots

typedef _Float16 f16x8 __attribute__((ext_vector_type(8)));
typedef float    f32x4 __attribute__((ext_vector_type(4)));

// async global->LDS DMA, 16 B per lane; lds base must be wave-uniform
#define GL16(gp, lp) __builtin_amdgcn_global_load_lds( \
    (const __attribute__((address_space(1))) unsigned int*)(gp), \
    (__attribute__((address_space(3))) unsigned int*)(lp), 16, 0, 0)

// ---------------- Kernel 1a: kinematics -> packed B panels + jout ----------
// Panel layout (both A and B): panel[tile][ks][slot=row*4+cs][8 f16], where
// the slot holds global chunk ci = cs ^ ((row>>1)&3) (bank swizzle), i.e.
// elements [row][k = ks*32 + ci*8 .. +7].
__global__ __launch_bounds__(256) void kin_kernel(
    const float* __restrict__ pose,         // (NB, NJ*3)
    const float* __restrict__ bone_lengths, // (NB, NBONES)
    const float* __restrict__ cbl,          // (NB)
    const float* __restrict__ trans,        // (NB, 3)
    const float* __restrict__ scale,        // (NB)
    const float* __restrict__ t_pose,       // (NJ, 3)
    const int*   __restrict__ parent,       // (NJ)
    const int*   __restrict__ bone_mapper,  // (NJ)
    _Float16* __restrict__ Bp,              // ws: (NBLK, KS, 512, 8)
    float* __restrict__ jout)               // (NB, NJ, 3)
{
    const int t = threadIdx.x;

    __shared__ float M0[NJ][12];
    __shared__ float M1[NJ][12];
    __shared__ int   a0[NJ];
    __shared__ int   a1[NJ];

    const int b = blockIdx.x;

    if (t < NJ) {
        const int j = t;
        float z = pose[b*(NJ*3) + 3*j + 0];
        float y = pose[b*(NJ*3) + 3*j + 1];
        float x = pose[b*(NJ*3) + 3*j + 2];
        float cx = cosf(x), sx = sinf(x);
        float cy = cosf(y), sy = sinf(y);
        float cz = cosf(z), sz = sinf(z);
        float r00 = cz*cy;
        float r01 = cz*sy*sx - sz*cx;
        float r02 = cz*sy*cx + sz*sx;
        float r10 = sz*cy;
        float r11 = sz*sy*sx + cz*cx;
        float r12 = sz*sy*cx - cz*sx;
        float r20 = -sy;
        float r21 = cy*sx;
        float r22 = cy*cx;
        float t0, t1, t2;
        int p = parent[j];
        if (j == 0) {
            t0 = t_pose[0]; t1 = t_pose[1]; t2 = t_pose[2];
        } else {
            float ox = t_pose[3*j+0] - t_pose[3*p+0];
            float oy = t_pose[3*j+1] - t_pose[3*p+1];
            float oz = t_pose[3*j+2] - t_pose[3*p+2];
            float s;
            if (j == 1) {
                s = cbl[b];
            } else {
                int blid = bone_mapper[j];
                if (blid >= 0) {
                    float bv = bone_lengths[b*NBONES + blid];
                    s = 2.0f / (1.0f + expf(-bv*0.2f));   // 2*sigmoid(x/5)
                } else {
                    s = 1.0f;
                }
            }
            t0 = ox*s; t1 = oy*s; t2 = oz*s;
        }
        M0[j][0]=r00; M0[j][1]=r01; M0[j][2]=r02;  M0[j][3]=t0;
        M0[j][4]=r10; M0[j][5]=r11; M0[j][6]=r12;  M0[j][7]=t1;
        M0[j][8]=r20; M0[j][9]=r21; M0[j][10]=r22; M0[j][11]=t2;
        a0[j] = (j == 0) ? -1 : p;
    }
    __syncthreads();

    float* src = &M0[0][0]; float* dst = &M1[0][0];
    int* as = a0; int* ad = a1;
    for (int r = 0; r < 8; ++r) {
        if (t < NJ) {
            int a = as[t];
            const float* Mi = src + t*12;
            float* Do = dst + t*12;
            if (a >= 0) {
                const float* Mp = src + a*12;
                #pragma unroll
                for (int m = 0; m < 3; ++m) {
                    float p0 = Mp[m*4+0], p1 = Mp[m*4+1], p2 = Mp[m*4+2], p3 = Mp[m*4+3];
                    Do[m*4+0] = p0*Mi[0] + p1*Mi[4] + p2*Mi[8];
                    Do[m*4+1] = p0*Mi[1] + p1*Mi[5] + p2*Mi[9];
                    Do[m*4+2] = p0*Mi[2] + p1*Mi[6] + p2*Mi[10];
                    Do[m*4+3] = p0*Mi[3] + p1*Mi[7] + p2*Mi[11] + p3;
                }
                ad[t] = as[a];
            } else {
                #pragma unroll
                for (int e = 0; e < 12; ++e) Do[e] = Mi[e];
                ad[t] = -1;
            }
        }
        __syncthreads();
        float* tf = src; src = dst; dst = tf;
        int* ti = as; as = ad; ad = ti;
    }

    // G_rel (fp32) into the spare LDS buffer, then pack to B panels
    float* grl = dst;   // dst != src after even # of swaps
    if (t < NJ) {
        const int j = t;
        const float* G = src + j*12;
        float sb = scale[b];
        float tr0 = trans[b*3+0], tr1 = trans[b*3+1], tr2 = trans[b*3+2];
        float* jo = jout + ((size_t)b*NJ + j)*3;
        jo[0] = G[3]*sb  + tr0;
        jo[1] = G[7]*sb  + tr1;
        jo[2] = G[11]*sb + tr2;
        float jx = t_pose[3*j+0], jy = t_pose[3*j+1], jz = t_pose[3*j+2];
        #pragma unroll
        for (int c = 0; c < 3; ++c) {
            float g0 = G[c*4+0], g1 = G[c*4+1], g2 = G[c*4+2];
            float g3 = G[c*4+3] - (g0*jx + g1*jy + g2*jz);
            grl[j*12 + c*4 + 0] = g0;
            grl[j*12 + c*4 + 1] = g1;
            grl[j*12 + c*4 + 2] = g2;
            grl[j*12 + c*4 + 3] = g3;
        }
    }
    __syncthreads();

    // pack: 3 rows x 18 ks x 4 ci = 216 f16x8 slots
    if (t < 216) {
        int c  = t / 72;
        int rr = t - c*72;
        int ks = rr >> 2;
        int ci = rr & 3;
        int nrow = b*3 + c;
        int nb = nrow >> 7;
        int rl = nrow & 127;
        int j0 = ks*8 + ci*2;
        f16x8 o;
        #pragma unroll
        for (int i = 0; i < 8; ++i) o[i] = (_Float16)0.f;
        if (j0 < NJ) {
            o[0] = (_Float16)grl[j0*12 + c*4 + 0];
            o[1] = (_Float16)grl[j0*12 + c*4 + 1];
            o[2] = (_Float16)grl[j0*12 + c*4 + 2];
            o[3] = (_Float16)grl[j0*12 + c*4 + 3];
        }
        if (j0 + 1 < NJ) {
            o[4] = (_Float16)grl[(j0+1)*12 + c*4 + 0];
            o[5] = (_Float16)grl[(j0+1)*12 + c*4 + 1];
            o[6] = (_Float16)grl[(j0+1)*12 + c*4 + 2];
            o[7] = (_Float16)grl[(j0+1)*12 + c*4 + 3];
        }
        int cs = ci ^ ((rl >> 1) & 3);
        *(f16x8*)(Bp + ((size_t)(nb*KS + ks)*512 + rl*4 + cs)*8) = o;
    }
}

// ---------------- Kernel 1b: A-prep (vectorized) ---------------------------
// One block per (mt, ks): 256 threads = 128 rows x 2 quads.
// Each thread: one float4 weights load -> two packed f16x8 slots (32 B).
__global__ __launch_bounds__(256) void aprep_kernel(
    const float* __restrict__ v_template,   // (NV, 3)
    const float* __restrict__ weights,      // (NV, NJ)
    _Float16* __restrict__ Ap)              // ws: (MTILES, KS, 512, 8)
{
    const int t   = threadIdx.x;
    const int mt  = blockIdx.x / KS;
    const int ks  = blockIdx.x - mt*KS;
    const int row = t >> 1;
    const int q   = t & 1;
    const int v   = mt*128 + row;
    const int j0  = ks*8 + q*4;
    const int s   = (row >> 1) & 3;

    f16x8 oA, oB;   // packs for chunks ci=2q and ci=2q+1
    #pragma unroll
    for (int i = 0; i < 8; ++i) { oA[i] = (_Float16)0.f; oB[i] = (_Float16)0.f; }

    if (v < NV && j0 + 3 < NJ) {           // NJ%8==4 -> per-quad all-or-nothing
        float x = v_template[v*3+0];
        float y = v_template[v*3+1];
        float z = v_template[v*3+2];
        const float4 w4 = *(const float4*)(weights + (size_t)v*NJ + j0);
        oA[0] = (_Float16)(w4.x*x); oA[1] = (_Float16)(w4.x*y);
        oA[2] = (_Float16)(w4.x*z); oA[3] = (_Float16)w4.x;
        oA[4] = (_Float16)(w4.y*x); oA[5] = (_Float16)(w4.y*y);
        oA[6] = (_Float16)(w4.y*z); oA[7] = (_Float16)w4.y;
        oB[0] = (_Float16)(w4.z*x); oB[1] = (_Float16)(w4.z*y);
        oB[2] = (_Float16)(w4.z*z); oB[3] = (_Float16)w4.z;
        oB[4] = (_Float16)(w4.w*x); oB[5] = (_Float16)(w4.w*y);
        oB[6] = (_Float16)(w4.w*z); oB[7] = (_Float16)w4.w;
    }

    // slot cs holds chunk ci = cs ^ s  =>  cs(2q) = (2q)^s, cs(2q+1) = cs(2q)^1
    const int base = ((2*q) ^ s) & ~1;     // even slot of the pair
    _Float16* dst = Ap + (((size_t)blockIdx.x)*512 + row*4 + base)*8;
    if (s & 1) {                            // odd slot first holds oB? no: cs(2q) is odd
        *(f16x8*)dst       = oB;            // slot base   = cs(2q+1)
        *(f16x8*)(dst + 8) = oA;            // slot base+1 = cs(2q)
    } else {
        *(f16x8*)dst       = oA;            // slot base   = cs(2q)
        *(f16x8*)(dst + 8) = oB;            // slot base+1 = cs(2q+1)
    }
}

// ---------------- Kernel 2: 3-deep-pipelined MFMA GEMM ---------------------
// 1236 blocks x 256 thr (4 waves 2m x 2n), tile 128x128, BK=32, 18 K-steps.
// XCD-bijective swizzle: each XCD owns ~155 contiguous (mt,nb) ids so A-panel
// reuse (12 nb per mt) hits its own L2 instead of HBM.
// Ring of 3 LDS buffers, counted s_waitcnt vmcnt(4): loads stay in flight
// across 2 barriers (never drained to 0 in steady state).
__global__ __launch_bounds__(256) void gemm_kernel(
    const _Float16* __restrict__ Ap,       // (MTILES, KS, 512, 8)
    const _Float16* __restrict__ Bp,       // (NBLK, KS, 512, 8)
    const float* __restrict__ scale,       // (NB)
    const float* __restrict__ trans,       // (NB*3) flat
    float* __restrict__ vout)              // (NB, NV, 3)
{
    __shared__ _Float16 sA[3][4096];       // 24 KB
    __shared__ _Float16 sB[3][4096];       // 24 KB  (48 KB total -> 3 blk/CU)

    const int t    = threadIdx.x;
    const int lane = t & 63;
    const int wid  = t >> 6;
    const int ln   = lane & 15;
    const int kq   = lane >> 4;
    const int wm   = wid & 1;
    const int wn   = wid >> 1;

    // bijective XCD swizzle (m204): nwg=1236, q=154, r=4
    const int q8 = GRID_GEMM >> 3;         // 154
    const int r8 = GRID_GEMM & 7;          // 4
    const int xcd = blockIdx.x & 7;
    const int idx = blockIdx.x >> 3;
    const int wgid = (xcd < r8 ? xcd*(q8+1) : r8*(q8+1) + (xcd-r8)*q8) + idx;

    const int mt = wgid / NBLK;
    const int nb = wgid - mt*NBLK;

    const _Float16* Ag = Ap + (size_t)mt*(KS*4096);
    const _Float16* Bg = Bp + (size_t)nb*(KS*4096);

    const int c1 = wid*64 + lane;          // staging chunk ids (16 B each)
    const int c2 = c1 + 256;
    const int lb1 = wid*512;               // wave-uniform LDS f16 offsets
    const int lb2 = 2048 + wid*512;

    // fragment read offsets (bank-swizzled; 2-way conflict = free)
    const int csl = kq ^ ((ln >> 1) & 3);
    const int rA  = wm*64 + ln;
    const int rB  = wn*64 + ln;
    const int afo = rA*32 + csl*8;         // + mi*512
    const int bfo = rB*32 + csl*8;         // + ni*512

    f32x4 acc[4][4];
    #pragma unroll
    for (int mi = 0; mi < 4; ++mi)
        #pragma unroll
        for (int ni = 0; ni < 4; ++ni)
            acc[mi][ni] = (f32x4){0.f, 0.f, 0.f, 0.f};

    auto stage = [&](int buf, int ks) {
        const _Float16* a = Ag + ks*4096;
        const _Float16* b = Bg + ks*4096;
        GL16(a + c1*8, &sA[buf][lb1]);
        GL16(a + c2*8, &sA[buf][lb2]);
        GL16(b + c1*8, &sB[buf][lb1]);
        GL16(b + c2*8, &sB[buf][lb2]);
    };
    auto compute = [&](int buf) {
        f16x8 af[4], bf[4];
        #pragma unroll
        for (int mi = 0; mi < 4; ++mi)
            af[mi] = *(const f16x8*)&sA[buf][afo + mi*512];
        #pragma unroll
        for (int ni = 0; ni < 4; ++ni)
            bf[ni] = *(const f16x8*)&sB[buf][bfo + ni*512];
        #pragma unroll
        for (int mi = 0; mi < 4; ++mi)
            #pragma unroll
            for (int ni = 0; ni < 4; ++ni)
                acc[mi][ni] = __builtin_amdgcn_mfma_f32_16x16x32_f16(
                    af[mi], bf[ni], acc[mi][ni], 0, 0, 0);
    };

    // each wave's own stage loads complete (vmcnt) before it joins the
    // barrier, so after the barrier the whole buffer is valid for all waves.
    #define WAITBAR4 do { \
        asm volatile("s_waitcnt vmcnt(4)" ::: "memory"); \
        __builtin_amdgcn_s_barrier(); } while (0)

    stage(0, 0);
    stage(1, 1);
    #pragma unroll 1
    for (int ks = 0; ks < KS - 3; ks += 3) {   // ks = 0,3,6,9,12
        WAITBAR4; stage(2, ks + 2); compute(0);
        WAITBAR4; stage(0, ks + 3); compute(1);
        WAITBAR4; stage(1, ks + 4); compute(2);
    }
    // computed 0..14, staged 0..16; remaining: 15(buf0), 16(buf1), 17(buf2)
    WAITBAR4; stage(2, 17); compute(0);        // ks = 15
    WAITBAR4; compute(1);                      // ks = 16
    asm volatile("s_waitcnt vmcnt(0)" ::: "memory");
    __builtin_amdgcn_s_barrier();
    compute(2);                                // ks = 17
    #undef WAITBAR4

    // ---- epilogue: direct scattered-dword stores ----
    long long obase[4]; float es[4], etr[4];
    #pragma unroll
    for (int ni = 0; ni < 4; ++ni) {
        int n  = nb*128 + wn*64 + ni*16 + ln;
        int bq = n / 3;
        int cr = n - bq*3;
        obase[ni] = (long long)bq*(NV*3) + cr;
        es[ni]  = scale[bq];
        etr[ni] = trans[n];
    }
    const int vb = mt*128 + wm*64 + kq*4;
    #pragma unroll
    for (int mi = 0; mi < 4; ++mi) {
        #pragma unroll
        for (int ni = 0; ni < 4; ++ni) {
            #pragma unroll
            for (int r = 0; r < 4; ++r) {
                int vg = vb + mi*16 + r;
                if (vg < NV)
                    vout[obase[ni] + (long long)vg*3] =
                        acc[mi][ni][r]*es[ni] + etr[ni];
            }
        }
    }
}

extern "C" void kernel_launch(void* const* d_in, const int* in_sizes, int n_in,
                              void* d_out, int out_size, void* d_ws, size_t ws_size,
                              hipStream_t stream) {
    const float* pose         = (const float*)d_in[0];
    const float* bone_lengths = (const float*)d_in[1];
    const float* cbl          = (const float*)d_in[2];
    const float* trans        = (const float*)d_in[3];
    const float* scale        = (const float*)d_in[4];
    const float* v_template   = (const float*)d_in[5];
    const float* t_pose       = (const float*)d_in[6];
    const float* weights      = (const float*)d_in[7];
    const int*   parent       = (const int*)d_in[8];
    const int*   bone_mapper  = (const int*)d_in[9];

    float* vout = (float*)d_out;                          // (NB,NV,3)
    float* jout = vout + (size_t)NB*NV*3;                 // (NB,NJ,3)

    _Float16* Ap = (_Float16*)d_ws;                       // 949248*16 B = 14.5 MB
    _Float16* Bp = Ap + (size_t)APREP_SLOTS*8;            // 12*18*512*16 B = 1.69 MB

    aprep_kernel<<<MTILES*KS, 256, 0, stream>>>(v_template, weights, Ap);
    kin_kernel<<<NB, 256, 0, stream>>>(
        pose, bone_lengths, cbl, trans, scale, t_pose,
        parent, bone_mapper, Bp, jout);
    gemm_kernel<<<GRID_GEMM, 256, 0, stream>>>(Ap, Bp, scale, trans, vout);
}